// Round 9
// baseline (115.746 us; speedup 1.0000x reference)
//
#include <hip/hip_runtime.h>
#include <hip/hip_bf16.h>
#include <cstdint>

typedef _Float16 f16;
typedef _Float16 f16x4 __attribute__((ext_vector_type(4)));
typedef _Float16 f16x8 __attribute__((ext_vector_type(8)));
typedef float f32x4 __attribute__((ext_vector_type(4)));

#define LNEG (-1e30f)
#define EXP2(x) __builtin_amdgcn_exp2f(x)   // bare v_exp_f32

__device__ __forceinline__ f32x4 mfma16(f16x8 a, f16x8 b, f32x4 c){
    return __builtin_amdgcn_mfma_f32_16x16x32_f16(a, b, c, 0, 0, 0);
}

// ---------- fused f32 -> f16 convert for x + 4 weights (contiguous dst) ----------
__global__ __launch_bounds__(256) void cvt5(
    const float* __restrict__ x,  const float* __restrict__ wq,
    const float* __restrict__ wk, const float* __restrict__ wv,
    const float* __restrict__ wp, f16* __restrict__ dst, int nx4, int nw4)
{
    int i = blockIdx.x * blockDim.x + threadIdx.x;
    const float* src; int off;
    if (i < nx4){ src = x; off = i; }
    else {
        int j = i - nx4;
        int s = j >> 18;              // nw4 == 2^18
        off = j & (nw4 - 1);
        src = (s == 0) ? wq : (s == 1) ? wk : (s == 2) ? wv : wp;
    }
    float4 v = ((const float4*)src)[off];
    f16x4 o = { (f16)v.x, (f16)v.y, (f16)v.z, (f16)v.w };
    *(f16x4*)&dst[(size_t)i * 4] = o;
}

// ---------- GEMM: reg-staged, XOR-swizzled LDS, double-buffered, 1 barrier/K-step ----
template<typename OutT>
__global__ __launch_bounds__(256) void gemm_xwt(
    const f16* __restrict__ A, const f16* __restrict__ W0, size_t wstride,
    OutT* __restrict__ out0, size_t ostride, f16* __restrict__ vtout,
    int M, int N, int K)
{
    const int tid  = threadIdx.x;
    const int lane = tid & 63;
    const int w    = tid >> 6;
    const int wr   = w >> 1, wc = w & 1;
    const int m0   = blockIdx.y * 128;
    const int n0   = blockIdx.x * 128;
    const f16* Wz  = W0 + wstride * blockIdx.z;
    OutT* out      = out0 + ostride * blockIdx.z;

    __shared__ f16 At[2][128 * 64];
    __shared__ f16 Bt[2][128 * 64];

    f32x4 acc[4][4] = {};
    f16x8 avr[4], bvr[4];

    int srow[4], scolb[4], sswz[4];
    #pragma unroll
    for (int j = 0; j < 4; ++j){
        int off  = (j * 256 + tid) * 16;
        srow[j]  = off >> 7;
        scolb[j] = off & 127;
        sswz[j]  = srow[j] * 128 + (scolb[j] ^ ((srow[j] & 7) << 4));
    }

    #pragma unroll
    for (int j = 0; j < 4; ++j){
        avr[j] = *(const f16x8*)&A [(size_t)(m0 + srow[j]) * K + (scolb[j] >> 1)];
        bvr[j] = *(const f16x8*)&Wz[(size_t)(n0 + srow[j]) * K + (scolb[j] >> 1)];
    }
    #pragma unroll
    for (int j = 0; j < 4; ++j){
        *(f16x8*)((char*)At[0] + sswz[j]) = avr[j];
        *(f16x8*)((char*)Bt[0] + sswz[j]) = bvr[j];
    }
    __syncthreads();

    const int NT = K >> 6;
    for (int t = 0; t < NT; ++t){
        const int cur = t & 1;
        const bool pre = (t + 1 < NT);
        if (pre){
            const int k0 = (t + 1) << 6;
            #pragma unroll
            for (int j = 0; j < 4; ++j){
                avr[j] = *(const f16x8*)&A [(size_t)(m0 + srow[j]) * K + k0 + (scolb[j] >> 1)];
                bvr[j] = *(const f16x8*)&Wz[(size_t)(n0 + srow[j]) * K + k0 + (scolb[j] >> 1)];
            }
        }
        #pragma unroll
        for (int kk = 0; kk < 2; ++kk){
            f16x8 af[4], bf[4];
            #pragma unroll
            for (int mf = 0; mf < 4; ++mf){
                int row = wr * 64 + mf * 16 + (lane & 15);
                int cb  = (kk * 64 + 16 * (lane >> 4)) ^ ((row & 7) << 4);
                af[mf] = *(const f16x8*)((const char*)At[cur] + row * 128 + cb);
            }
            #pragma unroll
            for (int nf = 0; nf < 4; ++nf){
                int row = wc * 64 + nf * 16 + (lane & 15);
                int cb  = (kk * 64 + 16 * (lane >> 4)) ^ ((row & 7) << 4);
                bf[nf] = *(const f16x8*)((const char*)Bt[cur] + row * 128 + cb);
            }
            #pragma unroll
            for (int mf = 0; mf < 4; ++mf)
                #pragma unroll
                for (int nf = 0; nf < 4; ++nf)
                    acc[mf][nf] = mfma16(af[mf], bf[nf], acc[mf][nf]);
        }
        if (pre){
            const int nb = cur ^ 1;
            #pragma unroll
            for (int j = 0; j < 4; ++j){
                *(f16x8*)((char*)At[nb] + sswz[j]) = avr[j];
                *(f16x8*)((char*)Bt[nb] + sswz[j]) = bvr[j];
            }
        }
        __syncthreads();
    }

    if (vtout != nullptr && blockIdx.z == 2){
        #pragma unroll
        for (int mf = 0; mf < 4; ++mf)
            #pragma unroll
            for (int nf = 0; nf < 4; ++nf){
                int row = m0 + wr * 64 + mf * 16 + 4 * (lane >> 4);
                int col = n0 + wc * 64 + nf * 16 + (lane & 15);
                int bb = row >> 11, ll = row & 2047;
                int bh = bb * 16 + (col >> 6), dd = col & 63;
                f16x4 o = { (f16)acc[mf][nf][0], (f16)acc[mf][nf][1],
                            (f16)acc[mf][nf][2], (f16)acc[mf][nf][3] };
                *(f16x4*)&vtout[((size_t)(bh * 64 + dd)) * 2048 + ll] = o;
            }
    } else {
        #pragma unroll
        for (int mf = 0; mf < 4; ++mf)
            #pragma unroll
            for (int nf = 0; nf < 4; ++nf)
                #pragma unroll
                for (int r = 0; r < 4; ++r){
                    int row = m0 + wr * 64 + mf * 16 + 4 * (lane >> 4) + r;
                    int col = n0 + wc * 64 + nf * 16 + (lane & 15);
                    out[(size_t)row * N + col] = (OutT)acc[mf][nf][r];
                }
    }
}

// ---------- fused causal flash attention, software-pipelined QK^T ----------
// 3 tiles in flight, 2 LDS buffers: QK^T(kt+1) issues BEFORE softmax(kt), so
// the MFMA pipe drains under the softmax VALU; stage(kt+2) lands in buf[kt&1]
// after PV(kt) frees it. amask ballot hoisted into the prefetch slot.
__global__ __launch_bounds__(256, 4) void attn_fused(
    const f16* __restrict__ q, const f16* __restrict__ k,
    const f16* __restrict__ vt, const int* __restrict__ amask,
    f16* __restrict__ y)
{
    const int tid  = threadIdx.x;
    const int lane = tid & 63;
    const int w    = tid >> 6;
    const int g    = lane >> 4;
    const int qq   = lane & 15;

    const int lin = blockIdx.x;
    const int bh  = ((lin & 7) << 2) | ((lin >> 3) & 3);
    const int qtv = (lin >> 5) & 31;
    const int q5  = (qtv & 7) | ((qtv & 16) >> 1);
    const int qt  = (qtv & 8) ? (31 - q5) : q5;
    const int b = bh >> 4, h = bh & 15;
    const int q0w = qt * 64 + w * 16;
    const int nkt = qt + 1;

    __shared__ char sK[2][64 * 128];
    __shared__ char sV[2][64 * 128];
    __shared__ char sP[4][16 * 128];

    const int srow = (tid * 2) >> 3;
    const int sc8a = (tid * 2) & 7, sc8b = sc8a + 1;
    const int swka = (sc8a * 16) ^ ((srow & 7) << 4);
    const int swkb = (sc8b * 16) ^ ((srow & 7) << 4);
    const f16* kbase  = k  + ((size_t)b * 2048) * 1024 + h * 64;
    const f16* vtbase = vt + (size_t)bh * 64 * 2048;

    const f16 qscale = (f16)(0.125f * 1.44269504088896f);
    f16x8 aq[2];
    #pragma unroll
    for (int f = 0; f < 2; ++f){
        aq[f] = *(const f16x8*)&q[((size_t)(b * 2048 + q0w + qq)) * 1024 + h * 64 + f * 32 + 8 * g];
        #pragma unroll
        for (int j = 0; j < 8; ++j) aq[f][j] *= qscale;
    }

    f32x4 acc_o[4] = {};
    float m_ln = LNEG, l_ln = 0.f;

    char* pbase = sP[w] + qq * 128;
    const int swp = (qq & 7) << 4;

    // ---- prologue: tile 0 -> buf0 ----
    {
        f16x8 ka  = *(const f16x8*)(kbase  + (size_t)srow * 1024 + sc8a * 8);
        f16x8 kb2 = *(const f16x8*)(kbase  + (size_t)srow * 1024 + sc8b * 8);
        f16x8 va  = *(const f16x8*)(vtbase + (size_t)srow * 2048 + sc8a * 8);
        f16x8 vb  = *(const f16x8*)(vtbase + (size_t)srow * 2048 + sc8b * 8);
        *(f16x8*)(sK[0] + srow * 128 + swka) = ka;
        *(f16x8*)(sK[0] + srow * 128 + swkb) = kb2;
        *(f16x8*)(sV[0] + srow * 128 + swka) = va;
        *(f16x8*)(sV[0] + srow * 128 + swkb) = vb;
    }
    __syncthreads();

    // ---- QK^T(0) + stage tile 1 -> buf1 ----
    f32x4 accA[4] = {};
    unsigned long long tok_cur;
    {
        const bool has1 = (nkt > 1);
        f16x8 ka, kb2, va, vb;
        if (has1){
            ka  = *(const f16x8*)(kbase  + (size_t)(64 + srow) * 1024 + sc8a * 8);
            kb2 = *(const f16x8*)(kbase  + (size_t)(64 + srow) * 1024 + sc8b * 8);
            va  = *(const f16x8*)(vtbase + (size_t)srow * 2048 + 64 + sc8a * 8);
            vb  = *(const f16x8*)(vtbase + (size_t)srow * 2048 + 64 + sc8b * 8);
        }
        const int amv0 = amask[b * 2048 + lane];
        #pragma unroll
        for (int kf = 0; kf < 4; ++kf){
            const int keyl = kf * 16 + qq;
            const char* kr = sK[0] + keyl * 128;
            const int sw = (keyl & 7) << 4;
            #pragma unroll
            for (int f = 0; f < 2; ++f){
                f16x8 ak = *(const f16x8*)(kr + ((f * 64 + 16 * g) ^ sw));
                accA[kf] = mfma16(ak, aq[f], accA[kf]);
            }
        }
        tok_cur = __ballot(amv0 != 0);
        if (has1){
            *(f16x8*)(sK[1] + srow * 128 + swka) = ka;
            *(f16x8*)(sK[1] + srow * 128 + swkb) = kb2;
            *(f16x8*)(sV[1] + srow * 128 + swka) = va;
            *(f16x8*)(sV[1] + srow * 128 + swkb) = vb;
        }
    }
    __syncthreads();

    for (int kt = 0; kt < nkt; ++kt){
        const int cur = kt & 1, nb = cur ^ 1;
        const int k0 = kt * 64;
        const bool has1 = (kt + 1 < nkt);
        const bool has2 = (kt + 2 < nkt);

        // prefetch tile kt+2 + next amask
        f16x8 ka, kb2, va, vb;
        int amv;
        if (has2){
            const int nk0 = k0 + 128;
            ka  = *(const f16x8*)(kbase  + (size_t)(nk0 + srow) * 1024 + sc8a * 8);
            kb2 = *(const f16x8*)(kbase  + (size_t)(nk0 + srow) * 1024 + sc8b * 8);
            va  = *(const f16x8*)(vtbase + (size_t)srow * 2048 + nk0 + sc8a * 8);
            vb  = *(const f16x8*)(vtbase + (size_t)srow * 2048 + nk0 + sc8b * 8);
        }
        if (has1) amv = amask[b * 2048 + k0 + 64 + lane];

        // QK^T(kt+1) — issues ahead; retires under softmax(kt)
        f32x4 accB[4] = {};
        if (has1){
            #pragma unroll
            for (int kf = 0; kf < 4; ++kf){
                const int keyl = kf * 16 + qq;
                const char* kr = sK[nb] + keyl * 128;
                const int sw = (keyl & 7) << 4;
                #pragma unroll
                for (int f = 0; f < 2; ++f){
                    f16x8 ak = *(const f16x8*)(kr + ((f * 64 + 16 * g) ^ sw));
                    accB[kf] = mfma16(ak, aq[f], accB[kf]);
                }
            }
        }

        // softmax(kt) on accA
        const bool tokall = (tok_cur == ~0ull);
        const bool fullt = (k0 + 63 <= q0w) && tokall;
        float sv[16];
        #pragma unroll
        for (int kf = 0; kf < 4; ++kf)
            #pragma unroll
            for (int r = 0; r < 4; ++r){
                float s = accA[kf][r];
                if (!fullt){
                    const int keyl = kf * 16 + 4 * g + r;
                    const bool ok = (k0 + keyl <= q0w + qq) && ((tok_cur >> keyl) & 1);
                    s = ok ? s : LNEG;
                }
                sv[kf * 4 + r] = s;
            }

        float tmax = sv[0];
        #pragma unroll
        for (int i = 1; i < 16; ++i) tmax = fmaxf(tmax, sv[i]);
        tmax = fmaxf(tmax, __shfl_xor(tmax, 16));
        tmax = fmaxf(tmax, __shfl_xor(tmax, 32));
        const bool skip = __all(tmax <= m_ln + 8.f);   // defer-max (log2 units)
        float alpha = 1.f;
        if (!skip){
            const float newm = fmaxf(m_ln, tmax);
            alpha = EXP2(m_ln - newm);
            m_ln = newm;
        }
        float rs = 0.f;
        #pragma unroll
        for (int i = 0; i < 16; ++i){ sv[i] = EXP2(sv[i] - m_ln); rs += sv[i]; }
        rs += __shfl_xor(rs, 16);
        rs += __shfl_xor(rs, 32);
        l_ln = l_ln * alpha + rs;
        if (!skip){
            #pragma unroll
            for (int r = 0; r < 4; ++r){
                const float ar = __shfl(alpha, 4 * g + r);
                #pragma unroll
                for (int nf = 0; nf < 4; ++nf) acc_o[nf][r] *= ar;
            }
        }

        #pragma unroll
        for (int kf = 0; kf < 4; ++kf){
            f16x4 pk = { (f16)sv[kf*4+0], (f16)sv[kf*4+1], (f16)sv[kf*4+2], (f16)sv[kf*4+3] };
            *(f16x4*)(pbase + ((kf * 32 + 8 * g) ^ swp)) = pk;
        }
        __builtin_amdgcn_wave_barrier();

        // PV(kt)
        #pragma unroll
        for (int f = 0; f < 2; ++f){
            f16x8 ap = *(const f16x8*)(pbase + ((f * 64 + 16 * g) ^ swp));
            #pragma unroll
            for (int nf = 0; nf < 4; ++nf){
                const int d = nf * 16 + qq;
                f16x8 bv = *(const f16x8*)(sV[cur] + d * 128 + ((f * 64 + 16 * g) ^ ((d & 7) << 4)));
                acc_o[nf] = mfma16(ap, bv, acc_o[nf]);
            }
        }

        // stage tile kt+2 into buf[cur] (freed by PV(kt))
        if (has2){
            __syncthreads();   // all waves done reading V(kt) in buf[cur]
            *(f16x8*)(sK[cur] + srow * 128 + swka) = ka;
            *(f16x8*)(sK[cur] + srow * 128 + swkb) = kb2;
            *(f16x8*)(sV[cur] + srow * 128 + swka) = va;
            *(f16x8*)(sV[cur] + srow * 128 + swkb) = vb;
            __syncthreads();   // visible before next iter's QK^T(kt+2)
        }
        if (has1) tok_cur = __ballot(amv != 0);
        #pragma unroll
        for (int i = 0; i < 4; ++i) accA[i] = accB[i];
    }

    const float invl = 1.f / l_ln;
    #pragma unroll
    for (int r = 0; r < 4; ++r){
        const float ir = __shfl(invl, 4 * g + r);
        const int row = q0w + 4 * g + r;
        #pragma unroll
        for (int nf = 0; nf < 4; ++nf)
            y[((size_t)(b * 2048 + row)) * 1024 + h * 64 + nf * 16 + qq] = (f16)(acc_o[nf][r] * ir);
    }
}

extern "C" void kernel_launch(void* const* d_in, const int* in_sizes, int n_in,
                              void* d_out, int out_size, void* d_ws, size_t ws_size,
                              hipStream_t stream){
    const float* x  = (const float*)d_in[0];
    const int*   am = (const int*)d_in[1];
    const float* Wq = (const float*)d_in[2];
    const float* Wk = (const float*)d_in[3];
    const float* Wv = (const float*)d_in[4];
    const float* Wp = (const float*)d_in[5];
    float* out = (float*)d_out;

    char* ws = (char*)d_ws;
    const size_t XE = (size_t)4096 * 1024;
    const size_t WE = (size_t)1024 * 1024;

    f16* x16 = (f16*)(ws);
    f16* w16 = (f16*)(ws + XE * 2);
    f16* qkv = (f16*)(ws + XE * 2 + WE * 8);
    f16* vt  = (f16*)(ws + XE * 2 + WE * 8 + XE * 6);
    f16* y16 = (f16*)(ws + XE * 2 + WE * 8 + XE * 8);

    cvt5<<<8192, 256, 0, stream>>>(x, Wq, Wk, Wv, Wp, x16,
                                   (int)(XE / 4), (int)(WE / 4));

    // z=0,1 -> q,k normal layout; z=2 -> V written TRANSPOSED into vt
    gemm_xwt<f16><<<dim3(8, 32, 3), 256, 0, stream>>>(x16, w16, WE, qkv, XE, vt, 4096, 1024, 1024);

    attn_fused<<<dim3(1024), 256, 0, stream>>>(qkv, qkv + XE, vt, am, y16);

    gemm_xwt<float><<<dim3(8, 32, 1), 256, 0, stream>>>(y16, w16 + 3 * WE, 0, out, 0, nullptr, 4096, 1024, 1024);
}